// Round 9
// baseline (437.447 us; speedup 1.0000x reference)
//
#include <hip/hip_runtime.h>
#include <hip/hip_bf16.h>
#include <cstdint>

// Problem constants
#define EMBED   192
#define DINNER  384
#define DSTATE  4
#define DCONV   4
#define DTRANK  12
#define NMIX    2
#define RANK    4
#define BB      8
#define LL      4096            // H*W = 64*64
#define NBL     (BB*LL)         // 32768 rows
#define NCHUNK  128
#define CLEN    32              // LL / NCHUNK

typedef __attribute__((ext_vector_type(8))) short short8;
typedef __attribute__((ext_vector_type(4))) float float4v;

static __device__ __forceinline__ ushort f2b(float f) {
    __hip_bfloat16 h = __float2bfloat16(f);
    return *(ushort*)&h;
}
static __device__ __forceinline__ float b2f(ushort u) {
    __hip_bfloat16 h;
    *(ushort*)&h = u;
    return __bfloat162float(h);
}
static __device__ __forceinline__ float bs2f(short s) {
    ushort u = (ushort)s;
    return b2f(u);
}

// ---------------------------------------------------------------------------
// Fused weight prep (one launch): wi cast | wo cast | xpw pad | dtw pad | cwT
// Region sizes: 294912 | 147456 | 24576 | 24576 | 3072  (total 494592)
// ---------------------------------------------------------------------------
#define PREP_N0 294912
#define PREP_N1 147456
#define PREP_N2 24576
#define PREP_N3 24576
#define PREP_N4 3072
__global__ __launch_bounds__(256) void k_prep(const float* __restrict__ in_proj_w,
                                              const float* __restrict__ out_proj_w,
                                              const float* __restrict__ x_proj_w,
                                              const float* __restrict__ dt_proj_w,
                                              const float* __restrict__ conv_w,
                                              ushort* __restrict__ wi,
                                              ushort* __restrict__ wo,
                                              ushort* __restrict__ xpwb,
                                              ushort* __restrict__ dtwpad,
                                              float* __restrict__ cwt) {
    int i = blockIdx.x * 256 + threadIdx.x;
    if (i < PREP_N0) {
        wi[i] = f2b(in_proj_w[i]);
        return;
    }
    i -= PREP_N0;
    if (i < PREP_N1) {
        wo[i] = f2b(out_proj_w[i]);
        return;
    }
    i -= PREP_N1;
    if (i < PREP_N2) {
        int mix = i / (32 * 384);
        int rem = i % (32 * 384);
        int e = rem / 384, k = rem % 384;
        xpwb[i] = (e < 20) ? f2b(x_proj_w[(size_t)mix * 20 * 384 + e * 384 + k]) : (ushort)0;
        return;
    }
    i -= PREP_N2;
    if (i < PREP_N3) {
        int mix = i / (384 * 32);
        int rem = i % (384 * 32);
        int n = rem / 32, r = rem % 32;
        dtwpad[i] = (r < DTRANK) ? f2b(dt_proj_w[(size_t)mix * 384 * DTRANK + n * DTRANK + r])
                                 : (ushort)0;
        return;
    }
    i -= PREP_N3;
    if (i < PREP_N4) {
        int mix = i / (DCONV * DINNER);
        int rem = i % (DCONV * DINNER);
        int k = rem / DINNER, d = rem % DINNER;
        cwt[i] = conv_w[(size_t)mix * DINNER * DCONV + d * DCONV + k];
    }
}

// ---------------------------------------------------------------------------
// Transpose (B, C, L) -> (B, L, C) bf16 (GEMM A operand + tail residual)
// ---------------------------------------------------------------------------
__global__ __launch_bounds__(256) void k_transpose(const float* __restrict__ x,
                                                   ushort* __restrict__ h0b) {
    __shared__ float tile[32][33];
    int b  = blockIdx.z;
    int c0 = blockIdx.y * 32;
    int l0 = blockIdx.x * 32;
    int tx = threadIdx.x;       // 0..31
    int ty = threadIdx.y;       // 0..7
    #pragma unroll
    for (int i = 0; i < 4; i++) {
        int c = c0 + ty + i * 8;
        tile[ty + i * 8][tx] = x[((size_t)b * EMBED + c) * LL + l0 + tx];
    }
    __syncthreads();
    #pragma unroll
    for (int i = 0; i < 4; i++) {
        int l = l0 + ty + i * 8;
        h0b[((size_t)b * LL + l) * EMBED + c0 + tx] = f2b(tile[tx][ty + i * 8]);
    }
}

// ---------------------------------------------------------------------------
// bf16 MFMA GEMM, NT: C[m,n] = sum_k A[m,k]*B[n,k]. M=32768 (grid.y*128).
// TN in {128 (WRN=2), 64 (WRN=1)}. BK=32. Writes fp32 C and/or bf16 Cb.
// ---------------------------------------------------------------------------
template<int TN, int WRN>
__global__ __launch_bounds__(256) void k_gemm_bf16(const ushort* __restrict__ A, int lda,
                                                   const ushort* __restrict__ Bw, int ldb,
                                                   float* __restrict__ C, int ldc,
                                                   ushort* __restrict__ Cb, int ldcb,
                                                   int K) {
    constexpr int WRM = 4 / WRN;
    constexpr int WM  = 128 / WRM;
    constexpr int MT  = WM / 16;
    __shared__ ushort As[128][40];
    __shared__ ushort Bs[TN][40];
    int tid  = threadIdx.x;
    int lane = tid & 63;
    int wave = tid >> 6;
    int wmo = (wave / WRN) * WM;
    int wno = (wave % WRN) * 64;
    int m0 = blockIdx.y * 128;
    int n0 = blockIdx.x * TN;

    float4v acc[MT][4];
    #pragma unroll
    for (int i = 0; i < MT; i++)
        #pragma unroll
        for (int j = 0; j < 4; j++)
            acc[i][j] = (float4v){0.f, 0.f, 0.f, 0.f};

    for (int k0 = 0; k0 < K; k0 += 32) {
        #pragma unroll
        for (int i = 0; i < 2; i++) {
            int idx = tid + i * 256;
            int r = idx >> 2, sg = idx & 3;
            *(short8*)&As[r][sg * 8] =
                *(const short8*)(A + (size_t)(m0 + r) * lda + k0 + sg * 8);
        }
        #pragma unroll
        for (int i = 0; i < TN / 64; i++) {
            int idx = tid + i * 256;
            int r = idx >> 2, sg = idx & 3;
            *(short8*)&Bs[r][sg * 8] =
                *(const short8*)(Bw + (size_t)(n0 + r) * ldb + k0 + sg * 8);
        }
        __syncthreads();
        short8 av[MT], bv[4];
        #pragma unroll
        for (int i = 0; i < MT; i++)
            av[i] = *(const short8*)&As[wmo + i * 16 + (lane & 15)][(lane >> 4) * 8];
        #pragma unroll
        for (int j = 0; j < 4; j++)
            bv[j] = *(const short8*)&Bs[wno + j * 16 + (lane & 15)][(lane >> 4) * 8];
        #pragma unroll
        for (int i = 0; i < MT; i++)
            #pragma unroll
            for (int j = 0; j < 4; j++)
                acc[i][j] = __builtin_amdgcn_mfma_f32_16x16x32_bf16(
                    av[i], bv[j], acc[i][j], 0, 0, 0);
        __syncthreads();
    }

    #pragma unroll
    for (int i = 0; i < MT; i++) {
        int rbase = m0 + wmo + i * 16 + (lane >> 4) * 4;
        #pragma unroll
        for (int j = 0; j < 4; j++) {
            int col = n0 + wno + j * 16 + (lane & 15);
            #pragma unroll
            for (int r = 0; r < 4; r++) {
                float v = acc[i][j][r];
                if (C)  C[(size_t)(rbase + r) * ldc + col] = v;
                if (Cb) Cb[(size_t)(rbase + r) * ldcb + col] = f2b(v);
            }
        }
    }
}

// ---------------------------------------------------------------------------
// Depthwise causal conv (width 4) + bias + SiLU.
// Thread owns 8 consecutive d x 8 consecutive l; sliding 4-row window in
// registers. Weights via transposed cwT (coalesced), paid once per 64 outputs.
// ---------------------------------------------------------------------------
__global__ __launch_bounds__(256) void k_conv_silu(const ushort* __restrict__ xz,
                                                   const float* __restrict__ cwt,
                                                   const float* __restrict__ cb,
                                                   ushort* __restrict__ xa) {
    int t   = blockIdx.x * 256 + threadIdx.x;   // over (NBL/8)*48
    int g   = t % 48;
    int blc = t / 48;
    int d0  = g * 8;
    int lc  = blc % (LL / 8);
    int b   = blc / (LL / 8);
    int l0  = lc * 8;

    float wk[4][8], bias[8];
    #pragma unroll
    for (int k = 0; k < 4; k++) {
        float4v wa = *(const float4v*)(cwt + k * DINNER + d0);
        float4v wb = *(const float4v*)(cwt + k * DINNER + d0 + 4);
        #pragma unroll
        for (int j = 0; j < 4; j++) { wk[k][j] = wa[j]; wk[k][j + 4] = wb[j]; }
    }
    {
        float4v ba = *(const float4v*)(cb + d0);
        float4v bb = *(const float4v*)(cb + d0 + 4);
        #pragma unroll
        for (int j = 0; j < 4; j++) { bias[j] = ba[j]; bias[j + 4] = bb[j]; }
    }

    float r0[8] = {}, r1[8] = {}, r2[8] = {};
    const ushort* px = xz + ((size_t)(b * LL + l0)) * 768 + d0;
    if (l0 > 0) {
        short8 v;
        v = *(const short8*)(px - 3 * 768);
        #pragma unroll
        for (int j = 0; j < 8; j++) r0[j] = bs2f(v[j]);
        v = *(const short8*)(px - 2 * 768);
        #pragma unroll
        for (int j = 0; j < 8; j++) r1[j] = bs2f(v[j]);
        v = *(const short8*)(px - 1 * 768);
        #pragma unroll
        for (int j = 0; j < 8; j++) r2[j] = bs2f(v[j]);
    }
    ushort* po = xa + ((size_t)(b * LL + l0)) * DINNER + d0;
    #pragma unroll
    for (int i = 0; i < 8; i++) {
        short8 v = *(const short8*)(px + (size_t)i * 768);
        float cur[8];
        #pragma unroll
        for (int j = 0; j < 8; j++) cur[j] = bs2f(v[j]);
        short8 ov;
        #pragma unroll
        for (int j = 0; j < 8; j++) {
            float a = bias[j] + wk[0][j] * r0[j] + wk[1][j] * r1[j]
                    + wk[2][j] * r2[j] + wk[3][j] * cur[j];
            float sv = a / (1.f + __expf(-a));
            ov[j] = (short)f2b(sv);
        }
        *(short8*)(po + (size_t)i * DINNER) = ov;
        #pragma unroll
        for (int j = 0; j < 8; j++) { r0[j] = r1[j]; r1[j] = r2[j]; r2[j] = cur[j]; }
    }
}

// ---------------------------------------------------------------------------
// Fused x_proj + dt_proj: per 128-row block.
// Phase 1: xdb = xa x xpw^T (K=384) -> xdb32 global + bf16 tile in LDS.
// Phase 2: dt = softplus(xdb16 x dtw^T + b) (K=32, zero-padded) -> dtv bf16.
// dt depends only on this block's rows, so the fusion is dependency-free.
// ---------------------------------------------------------------------------
__global__ __launch_bounds__(256) void k_xproj_dt(const ushort* __restrict__ xa,
                                                  const ushort* __restrict__ xpwb,
                                                  const ushort* __restrict__ dtwpad,
                                                  const float* __restrict__ dtb,
                                                  float* __restrict__ xdb32,
                                                  ushort* __restrict__ dtv) {
    __shared__ ushort As[128][40];
    __shared__ ushort Bs[32][40];
    __shared__ ushort Xs[128][40];   // xdb16 tile
    int tid  = threadIdx.x;
    int lane = tid & 63;
    int wave = tid >> 6;
    int m0 = blockIdx.x * 128;
    float4v acc[2][2];
    #pragma unroll
    for (int i = 0; i < 2; i++)
        #pragma unroll
        for (int j = 0; j < 2; j++)
            acc[i][j] = (float4v){0.f, 0.f, 0.f, 0.f};
    for (int k0 = 0; k0 < 384; k0 += 32) {
        #pragma unroll
        for (int i = 0; i < 2; i++) {
            int idx = tid + i * 256;
            int r = idx >> 2, sg = idx & 3;
            *(short8*)&As[r][sg * 8] =
                *(const short8*)(xa + (size_t)(m0 + r) * 384 + k0 + sg * 8);
        }
        if (tid < 128) {
            int r = tid >> 2, sg = tid & 3;
            *(short8*)&Bs[r][sg * 8] =
                *(const short8*)(xpwb + (size_t)r * 384 + k0 + sg * 8);
        }
        __syncthreads();
        short8 av[2], bv[2];
        #pragma unroll
        for (int i = 0; i < 2; i++)
            av[i] = *(const short8*)&As[wave * 32 + i * 16 + (lane & 15)][(lane >> 4) * 8];
        #pragma unroll
        for (int j = 0; j < 2; j++)
            bv[j] = *(const short8*)&Bs[j * 16 + (lane & 15)][(lane >> 4) * 8];
        #pragma unroll
        for (int i = 0; i < 2; i++)
            #pragma unroll
            for (int j = 0; j < 2; j++)
                acc[i][j] = __builtin_amdgcn_mfma_f32_16x16x32_bf16(
                    av[i], bv[j], acc[i][j], 0, 0, 0);
        __syncthreads();
    }
    #pragma unroll
    for (int i = 0; i < 2; i++) {
        int rloc = wave * 32 + i * 16 + (lane >> 4) * 4;
        #pragma unroll
        for (int j = 0; j < 2; j++) {
            int col = j * 16 + (lane & 15);
            #pragma unroll
            for (int r = 0; r < 4; r++) {
                float v = acc[i][j][r];
                xdb32[(size_t)(m0 + rloc + r) * 32 + col] = v;
                Xs[rloc + r][col] = f2b(v);
            }
        }
    }
    __syncthreads();
    // Phase 2: dt GEMM over this block's 128 rows (wave handles 32 rows).
    int ak = (lane >> 4) * 8;
    #pragma unroll
    for (int rt = 0; rt < 2; rt++) {
        int rowb = wave * 32 + rt * 16;
        short8 av = *(const short8*)&Xs[rowb + (lane & 15)][ak];
        int rbase = m0 + rowb + (lane >> 4) * 4;
        #pragma unroll
        for (int j = 0; j < 24; j++) {
            int col = j * 16 + (lane & 15);
            short8 bv = *(const short8*)(dtwpad + (size_t)col * 32 + ak);
            float4v dacc = (float4v){0.f, 0.f, 0.f, 0.f};
            dacc = __builtin_amdgcn_mfma_f32_16x16x32_bf16(av, bv, dacc, 0, 0, 0);
            float bias = dtb[col];
            #pragma unroll
            for (int r = 0; r < 4; r++) {
                float s = dacc[r] + bias;
                float sp = fmaxf(s, 0.f) + __logf(1.f + __expf(-fabsf(s)));
                dtv[(size_t)(rbase + r) * DINNER + col] = f2b(sp);
            }
        }
    }
}

// ---------------------------------------------------------------------------
// Chunked scan pass 1: per-chunk local scan from h=0.
// Carry layout chunk-major: carryH[(chunk*BB+b)*1536 + d*4+s] (float4 store),
// carryT = sum(dt) over chunk (1 float; A-prod recomputed as exp(As*T)).
// ---------------------------------------------------------------------------
__global__ __launch_bounds__(384) void k_scan_local(const ushort* __restrict__ xa,
                                                    const float* __restrict__ xdb32,
                                                    const ushort* __restrict__ dtvb,
                                                    const float* __restrict__ A_log,
                                                    float* __restrict__ carryT,
                                                    float* __restrict__ carryH) {
    int d     = threadIdx.x;
    int chunk = blockIdx.x;
    int b     = blockIdx.y;
    __shared__ float rows[CLEN * 32];
    size_t rbase = ((size_t)b * LL + (size_t)chunk * CLEN) * 32;
    for (int i = d; i < CLEN * 32; i += 384) rows[i] = xdb32[rbase + i];
    float As[DSTATE];
    #pragma unroll
    for (int s = 0; s < DSTATE; s++) As[s] = -__expf(A_log[d * DSTATE + s]);
    __syncthreads();
    float h[DSTATE] = {0.f, 0.f, 0.f, 0.f};
    float T = 0.f;
    size_t mbase = (size_t)b * LL + (size_t)chunk * CLEN;
    for (int l = 0; l < CLEN; l++) {
        size_t m = mbase + l;
        float dtvv = b2f(dtvb[m * DINNER + d]);
        float xav  = b2f(xa[m * DINNER + d]);
        float du   = dtvv * xav;
        T += dtvv;
        const float* row = &rows[l * 32];
        #pragma unroll
        for (int s = 0; s < DSTATE; s++) {
            float da = __expf(dtvv * As[s]);
            h[s] = da * h[s] + du * row[DTRANK + s];
        }
    }
    size_t cb = ((size_t)chunk * BB + b);
    carryT[cb * 384 + d] = T;
    float4v hv = {h[0], h[1], h[2], h[3]};
    *(float4v*)(carryH + cb * 1536 + d * 4) = hv;
}

// ---------------------------------------------------------------------------
// Pass 2: one thread per chain (b,d,s), serial over 128 chunks with
// coalesced per-step loads. A_k = exp(As * T_k). Writes incoming state
// (exclusive prefix) to carryI.
// ---------------------------------------------------------------------------
__global__ __launch_bounds__(256) void k_scan_combine(const float* __restrict__ carryT,
                                                      const float* __restrict__ carryH,
                                                      const float* __restrict__ A_log,
                                                      float* __restrict__ carryI) {
    int c   = blockIdx.x * 256 + threadIdx.x;   // 0..12287
    int b   = c / 1536;
    int rem = c - b * 1536;                     // d*4+s
    int d   = rem >> 2;
    float As = -__expf(A_log[rem]);
    float hrun = 0.f;
    for (int k = 0; k < NCHUNK; k++) {
        size_t o = (size_t)k * BB + b;
        float T  = carryT[o * 384 + d];
        float Hk = carryH[o * 1536 + rem];
        carryI[o * 1536 + rem] = hrun;
        hrun = __expf(As * T) * hrun + Hk;
    }
}

// ---------------------------------------------------------------------------
// Pass 3: seeded rerun; y = h·C + xa*D, y *= silu(z); write bf16 y.
// ---------------------------------------------------------------------------
__global__ __launch_bounds__(384) void k_scan_final(const ushort* __restrict__ xa,
                                                    const ushort* __restrict__ xz,
                                                    const float* __restrict__ xdb32,
                                                    const ushort* __restrict__ dtvb,
                                                    const float* __restrict__ A_log,
                                                    const float* __restrict__ Dp,
                                                    const float* __restrict__ carryI,
                                                    ushort* __restrict__ y) {
    int d     = threadIdx.x;
    int chunk = blockIdx.x;
    int b     = blockIdx.y;
    __shared__ float rows[CLEN * 32];
    size_t rbase = ((size_t)b * LL + (size_t)chunk * CLEN) * 32;
    for (int i = d; i < CLEN * 32; i += 384) rows[i] = xdb32[rbase + i];
    float As[DSTATE];
    #pragma unroll
    for (int s = 0; s < DSTATE; s++) As[s] = -__expf(A_log[d * DSTATE + s]);
    float Dd = Dp[d];
    float4v hv = *(const float4v*)(carryI + ((size_t)chunk * BB + b) * 1536 + d * 4);
    float h[DSTATE];
    #pragma unroll
    for (int s = 0; s < DSTATE; s++) h[s] = hv[s];
    __syncthreads();
    size_t mbase = (size_t)b * LL + (size_t)chunk * CLEN;
    for (int l = 0; l < CLEN; l++) {
        size_t m = mbase + l;
        float dtvv = b2f(dtvb[m * DINNER + d]);
        float xav  = b2f(xa[m * DINNER + d]);
        float du   = dtvv * xav;
        const float* row = &rows[l * 32];
        float yv = 0.f;
        #pragma unroll
        for (int s = 0; s < DSTATE; s++) {
            float da = __expf(dtvv * As[s]);
            h[s] = da * h[s] + du * row[DTRANK + s];
            yv  += h[s] * row[DTRANK + DSTATE + s];
        }
        yv += xav * Dd;
        float zv = b2f(xz[m * 768 + DINNER + d]);
        yv *= zv / (1.f + __expf(-zv));
        y[m * DINNER + d] = f2b(yv);
    }
}

// ---------------------------------------------------------------------------
// Tail: low-rank (U,V) + residual(h0b, bf16) + LayerNorm; LDS-staged
// coalesced (B,C,L) writes. Residual from h0b saves the 100 MB fp32 x read.
// ---------------------------------------------------------------------------
__global__ __launch_bounds__(256) void k_tail(const ushort* __restrict__ h1b,
                                              const ushort* __restrict__ h0b,
                                              const float* __restrict__ U,
                                              const float* __restrict__ V,
                                              const float* __restrict__ g,
                                              const float* __restrict__ be,
                                              float* __restrict__ out) {
    __shared__ float tile[EMBED * 65];
    int tid  = threadIdx.x;
    int lane = tid & 63;
    int wave = tid >> 6;
    int b  = blockIdx.y;
    int l0 = blockIdx.x * 64;
    for (int t = 0; t < 16; t++) {
        int lloc = wave * 16 + t;
        size_t m = (size_t)b * LL + l0 + lloc;
        float hv[3];
        #pragma unroll
        for (int i = 0; i < 3; i++) hv[i] = b2f(h1b[m * EMBED + lane + 64 * i]);
        float r[RANK];
        #pragma unroll
        for (int j = 0; j < RANK; j++) {
            float p = 0.f;
            #pragma unroll
            for (int i = 0; i < 3; i++) p += hv[i] * U[j * EMBED + lane + 64 * i];
            #pragma unroll
            for (int off = 1; off < 64; off <<= 1) p += __shfl_xor(p, off);
            r[j] = p;
        }
        float u[3], s1 = 0.f, s2 = 0.f;
        #pragma unroll
        for (int i = 0; i < 3; i++) {
            int c = lane + 64 * i;
            float v = r[0] * V[c * 4 + 0] + r[1] * V[c * 4 + 1]
                    + r[2] * V[c * 4 + 2] + r[3] * V[c * 4 + 3];
            u[i] = v + b2f(h0b[m * EMBED + c]);
            s1 += u[i];
            s2 += u[i] * u[i];
        }
        #pragma unroll
        for (int off = 1; off < 64; off <<= 1) {
            s1 += __shfl_xor(s1, off);
            s2 += __shfl_xor(s2, off);
        }
        float mean = s1 * (1.f / EMBED);
        float var  = s2 * (1.f / EMBED) - mean * mean;
        float inv  = rsqrtf(var + 1e-5f);
        #pragma unroll
        for (int i = 0; i < 3; i++) {
            int c = lane + 64 * i;
            tile[c * 65 + lloc] = (u[i] - mean) * inv * g[c] + be[c];
        }
    }
    __syncthreads();
    for (int i = tid; i < EMBED * 64; i += 256) {
        int c = i >> 6, l = i & 63;
        out[((size_t)(b * EMBED + c)) * LL + l0 + l] = tile[c * 65 + l];
    }
}

// ---------------------------------------------------------------------------
extern "C" void kernel_launch(void* const* d_in, const int* in_sizes, int n_in,
                              void* d_out, int out_size, void* d_ws, size_t ws_size,
                              hipStream_t stream) {
    const float* x          = (const float*)d_in[0];
    const float* in_proj_w  = (const float*)d_in[1];
    const float* conv_w     = (const float*)d_in[2];
    const float* conv_b     = (const float*)d_in[3];
    const float* x_proj_w   = (const float*)d_in[4];
    const float* dt_proj_w  = (const float*)d_in[5];
    const float* dt_proj_b  = (const float*)d_in[6];
    const float* A_log      = (const float*)d_in[7];
    const float* Dp         = (const float*)d_in[8];
    const float* out_proj_w = (const float*)d_in[9];
    const float* U_w        = (const float*)d_in[10];
    const float* V_w        = (const float*)d_in[11];
    const float* ln_g       = (const float*)d_in[12];
    const float* ln_b       = (const float*)d_in[13];
    float* out = (float*)d_out;

    // Workspace layout.
    float* ws    = (float*)d_ws;
    float* xdb32 = ws;                                     // NBL*32 f32
    float* carryT = xdb32 + (size_t)NBL * 32;              // 128*8*384 f32
    float* carryH = carryT + (size_t)NCHUNK * BB * DINNER; // 128*8*1536 f32
    float* carryI = carryH + (size_t)NCHUNK * BB * DINNER * DSTATE;
    ushort* dtv    = (ushort*)(carryI + (size_t)NCHUNK * BB * DINNER * DSTATE);
    ushort* xz16   = dtv    + (size_t)NBL * DINNER;
    ushort* xa16   = xz16   + (size_t)NBL * 768;
    ushort* yb     = xa16   + (size_t)NBL * DINNER;
    ushort* h0b    = yb     + (size_t)NBL * DINNER;
    ushort* h1b    = h0b    + (size_t)NBL * EMBED;
    ushort* wi     = h1b    + (size_t)NBL * EMBED;         // 2*768*192
    ushort* wo     = wi     + (size_t)NMIX * 768 * EMBED;  // 2*192*384
    ushort* xpwb   = wo     + (size_t)NMIX * EMBED * DINNER; // 2*32*384
    ushort* dtwpad = xpwb   + (size_t)NMIX * 32 * 384;       // 2*384*32
    float*  cwt    = (float*)(dtwpad + (size_t)NMIX * 384 * 32); // 2*4*384 f32

    // fused weight prep (one launch)
    k_prep<<<(PREP_N0 + PREP_N1 + PREP_N2 + PREP_N3 + PREP_N4) / 256, 256, 0, stream>>>(
        in_proj_w, out_proj_w, x_proj_w, dt_proj_w, conv_w, wi, wo, xpwb, dtwpad, cwt);

    k_transpose<<<dim3(LL / 32, EMBED / 32, BB), dim3(32, 8), 0, stream>>>(x, h0b);

    const ushort* hinb = h0b;
    for (int mix = 0; mix < NMIX; mix++) {
        const float* Alg = A_log + (size_t)mix * DINNER * DSTATE;

        // in_proj -> xz bf16 (NBL,768)
        k_gemm_bf16<128, 2><<<dim3(768 / 128, NBL / 128), 256, 0, stream>>>(
            hinb, EMBED, wi + (size_t)mix * 768 * EMBED, EMBED,
            (float*)nullptr, 0, xz16, 768, EMBED);
        // conv + silu -> xa bf16 (sliding window, 8l x 8d per thread)
        k_conv_silu<<<(NBL / 8 * 48) / 256, 256, 0, stream>>>(
            xz16, cwt + (size_t)mix * DCONV * DINNER, conv_b + mix * DINNER, xa16);
        // fused x_proj + dt_proj -> xdb32 f32 + dtv bf16
        k_xproj_dt<<<NBL / 128, 256, 0, stream>>>(
            xa16, xpwb + (size_t)mix * 32 * 384, dtwpad + (size_t)mix * 384 * 32,
            dt_proj_b + mix * DINNER, xdb32, dtv);
        // chunked scan (chunk-major carries, coalesced)
        k_scan_local<<<dim3(NCHUNK, BB), 384, 0, stream>>>(
            xa16, xdb32, dtv, Alg, carryT, carryH);
        k_scan_combine<<<(BB * DINNER * DSTATE) / 256, 256, 0, stream>>>(
            carryT, carryH, Alg, carryI);
        k_scan_final<<<dim3(NCHUNK, BB), 384, 0, stream>>>(
            xa16, xz16, xdb32, dtv, Alg, Dp + mix * DINNER, carryI, yb);
        // out_proj -> h1b bf16 only
        k_gemm_bf16<64, 1><<<dim3(EMBED / 64, NBL / 128), 256, 0, stream>>>(
            yb, DINNER, wo + (size_t)mix * EMBED * DINNER, DINNER,
            (float*)nullptr, 0, h1b, EMBED, DINNER);
        hinb = h1b;
    }

    // tail: low-rank + residual(h0b) + LayerNorm -> out (B,C,H,W)
    k_tail<<<dim3(LL / 64, BB), 256, 0, stream>>>(h1b, h0b, U_w, V_w, ln_g, ln_b, out);
}

// Round 10
// 427.577 us; speedup vs baseline: 1.0231x; 1.0231x over previous
//
#include <hip/hip_runtime.h>
#include <hip/hip_bf16.h>
#include <cstdint>

// Problem constants
#define EMBED   192
#define DINNER  384
#define DSTATE  4
#define DCONV   4
#define DTRANK  12
#define NMIX    2
#define RANK    4
#define BB      8
#define LL      4096            // H*W = 64*64
#define NBL     (BB*LL)         // 32768 rows
#define NCHUNK  128
#define CLEN    32              // LL / NCHUNK

typedef __attribute__((ext_vector_type(8))) short short8;
typedef __attribute__((ext_vector_type(4))) float float4v;

static __device__ __forceinline__ ushort f2b(float f) {
    __hip_bfloat16 h = __float2bfloat16(f);
    return *(ushort*)&h;
}
static __device__ __forceinline__ float b2f(ushort u) {
    __hip_bfloat16 h;
    *(ushort*)&h = u;
    return __bfloat162float(h);
}
static __device__ __forceinline__ float bs2f(short s) {
    ushort u = (ushort)s;
    return b2f(u);
}

// ---------------------------------------------------------------------------
// Fused weight prep (one launch): wi cast | wo cast | xpw pad | dtw^T | cwT
// Region sizes: 294912 | 147456 | 24576 | 9216 | 3072  (total 479232)
// ---------------------------------------------------------------------------
#define PREP_N0 294912
#define PREP_N1 147456
#define PREP_N2 24576
#define PREP_N3 9216
#define PREP_N4 3072
__global__ __launch_bounds__(256) void k_prep(const float* __restrict__ in_proj_w,
                                              const float* __restrict__ out_proj_w,
                                              const float* __restrict__ x_proj_w,
                                              const float* __restrict__ dt_proj_w,
                                              const float* __restrict__ conv_w,
                                              ushort* __restrict__ wi,
                                              ushort* __restrict__ wo,
                                              ushort* __restrict__ xpwb,
                                              float* __restrict__ dtwT,
                                              float* __restrict__ cwt) {
    int i = blockIdx.x * 256 + threadIdx.x;
    if (i < PREP_N0) {
        wi[i] = f2b(in_proj_w[i]);
        return;
    }
    i -= PREP_N0;
    if (i < PREP_N1) {
        wo[i] = f2b(out_proj_w[i]);
        return;
    }
    i -= PREP_N1;
    if (i < PREP_N2) {
        int mix = i / (32 * 384);
        int rem = i % (32 * 384);
        int e = rem / 384, k = rem % 384;
        xpwb[i] = (e < 20) ? f2b(x_proj_w[(size_t)mix * 20 * 384 + e * 384 + k]) : (ushort)0;
        return;
    }
    i -= PREP_N2;
    if (i < PREP_N3) {
        // dtwT[mix][r][d] = dt_proj_w[mix][d][r]  (fp32, lane-coalesced in d)
        int mix = i / (DTRANK * 384);
        int rem = i % (DTRANK * 384);
        int r = rem / 384, d = rem % 384;
        dtwT[i] = dt_proj_w[(size_t)mix * 384 * DTRANK + d * DTRANK + r];
        return;
    }
    i -= PREP_N3;
    if (i < PREP_N4) {
        int mix = i / (DCONV * DINNER);
        int rem = i % (DCONV * DINNER);
        int k = rem / DINNER, d = rem % DINNER;
        cwt[i] = conv_w[(size_t)mix * DINNER * DCONV + d * DCONV + k];
    }
}

// ---------------------------------------------------------------------------
// Transpose (B, C, L) -> (B, L, C) bf16 (GEMM A operand + tail residual)
// ---------------------------------------------------------------------------
__global__ __launch_bounds__(256) void k_transpose(const float* __restrict__ x,
                                                   ushort* __restrict__ h0b) {
    __shared__ float tile[32][33];
    int b  = blockIdx.z;
    int c0 = blockIdx.y * 32;
    int l0 = blockIdx.x * 32;
    int tx = threadIdx.x;       // 0..31
    int ty = threadIdx.y;       // 0..7
    #pragma unroll
    for (int i = 0; i < 4; i++) {
        int c = c0 + ty + i * 8;
        tile[ty + i * 8][tx] = x[((size_t)b * EMBED + c) * LL + l0 + tx];
    }
    __syncthreads();
    #pragma unroll
    for (int i = 0; i < 4; i++) {
        int l = l0 + ty + i * 8;
        h0b[((size_t)b * LL + l) * EMBED + c0 + tx] = f2b(tile[tx][ty + i * 8]);
    }
}

// ---------------------------------------------------------------------------
// bf16 MFMA GEMM, NT: C[m,n] = sum_k A[m,k]*B[n,k]. M=32768 (grid.y*128).
// TN in {128 (WRN=2), 64 (WRN=1)}. BK=32. Writes fp32 C and/or bf16 Cb.
// ---------------------------------------------------------------------------
template<int TN, int WRN>
__global__ __launch_bounds__(256) void k_gemm_bf16(const ushort* __restrict__ A, int lda,
                                                   const ushort* __restrict__ Bw, int ldb,
                                                   float* __restrict__ C, int ldc,
                                                   ushort* __restrict__ Cb, int ldcb,
                                                   int K) {
    constexpr int WRM = 4 / WRN;
    constexpr int WM  = 128 / WRM;
    constexpr int MT  = WM / 16;
    __shared__ ushort As[128][40];
    __shared__ ushort Bs[TN][40];
    int tid  = threadIdx.x;
    int lane = tid & 63;
    int wave = tid >> 6;
    int wmo = (wave / WRN) * WM;
    int wno = (wave % WRN) * 64;
    int m0 = blockIdx.y * 128;
    int n0 = blockIdx.x * TN;

    float4v acc[MT][4];
    #pragma unroll
    for (int i = 0; i < MT; i++)
        #pragma unroll
        for (int j = 0; j < 4; j++)
            acc[i][j] = (float4v){0.f, 0.f, 0.f, 0.f};

    for (int k0 = 0; k0 < K; k0 += 32) {
        #pragma unroll
        for (int i = 0; i < 2; i++) {
            int idx = tid + i * 256;
            int r = idx >> 2, sg = idx & 3;
            *(short8*)&As[r][sg * 8] =
                *(const short8*)(A + (size_t)(m0 + r) * lda + k0 + sg * 8);
        }
        #pragma unroll
        for (int i = 0; i < TN / 64; i++) {
            int idx = tid + i * 256;
            int r = idx >> 2, sg = idx & 3;
            *(short8*)&Bs[r][sg * 8] =
                *(const short8*)(Bw + (size_t)(n0 + r) * ldb + k0 + sg * 8);
        }
        __syncthreads();
        short8 av[MT], bv[4];
        #pragma unroll
        for (int i = 0; i < MT; i++)
            av[i] = *(const short8*)&As[wmo + i * 16 + (lane & 15)][(lane >> 4) * 8];
        #pragma unroll
        for (int j = 0; j < 4; j++)
            bv[j] = *(const short8*)&Bs[wno + j * 16 + (lane & 15)][(lane >> 4) * 8];
        #pragma unroll
        for (int i = 0; i < MT; i++)
            #pragma unroll
            for (int j = 0; j < 4; j++)
                acc[i][j] = __builtin_amdgcn_mfma_f32_16x16x32_bf16(
                    av[i], bv[j], acc[i][j], 0, 0, 0);
        __syncthreads();
    }

    #pragma unroll
    for (int i = 0; i < MT; i++) {
        int rbase = m0 + wmo + i * 16 + (lane >> 4) * 4;
        #pragma unroll
        for (int j = 0; j < 4; j++) {
            int col = n0 + wno + j * 16 + (lane & 15);
            #pragma unroll
            for (int r = 0; r < 4; r++) {
                float v = acc[i][j][r];
                if (C)  C[(size_t)(rbase + r) * ldc + col] = v;
                if (Cb) Cb[(size_t)(rbase + r) * ldcb + col] = f2b(v);
            }
        }
    }
}

// ---------------------------------------------------------------------------
// Depthwise causal conv (width 4) + bias + SiLU.
// Thread owns 8 consecutive d x 8 consecutive l; sliding 4-row window in
// registers. Weights via transposed cwT (coalesced), paid once per 64 outputs.
// ---------------------------------------------------------------------------
__global__ __launch_bounds__(256) void k_conv_silu(const ushort* __restrict__ xz,
                                                   const float* __restrict__ cwt,
                                                   const float* __restrict__ cb,
                                                   ushort* __restrict__ xa) {
    int t   = blockIdx.x * 256 + threadIdx.x;   // over (NBL/8)*48
    int g   = t % 48;
    int blc = t / 48;
    int d0  = g * 8;
    int lc  = blc % (LL / 8);
    int b   = blc / (LL / 8);
    int l0  = lc * 8;

    float wk[4][8], bias[8];
    #pragma unroll
    for (int k = 0; k < 4; k++) {
        float4v wa = *(const float4v*)(cwt + k * DINNER + d0);
        float4v wb = *(const float4v*)(cwt + k * DINNER + d0 + 4);
        #pragma unroll
        for (int j = 0; j < 4; j++) { wk[k][j] = wa[j]; wk[k][j + 4] = wb[j]; }
    }
    {
        float4v ba = *(const float4v*)(cb + d0);
        float4v bb = *(const float4v*)(cb + d0 + 4);
        #pragma unroll
        for (int j = 0; j < 4; j++) { bias[j] = ba[j]; bias[j + 4] = bb[j]; }
    }

    float r0[8] = {}, r1[8] = {}, r2[8] = {};
    const ushort* px = xz + ((size_t)(b * LL + l0)) * 768 + d0;
    if (l0 > 0) {
        short8 v;
        v = *(const short8*)(px - 3 * 768);
        #pragma unroll
        for (int j = 0; j < 8; j++) r0[j] = bs2f(v[j]);
        v = *(const short8*)(px - 2 * 768);
        #pragma unroll
        for (int j = 0; j < 8; j++) r1[j] = bs2f(v[j]);
        v = *(const short8*)(px - 1 * 768);
        #pragma unroll
        for (int j = 0; j < 8; j++) r2[j] = bs2f(v[j]);
    }
    ushort* po = xa + ((size_t)(b * LL + l0)) * DINNER + d0;
    #pragma unroll
    for (int i = 0; i < 8; i++) {
        short8 v = *(const short8*)(px + (size_t)i * 768);
        float cur[8];
        #pragma unroll
        for (int j = 0; j < 8; j++) cur[j] = bs2f(v[j]);
        short8 ov;
        #pragma unroll
        for (int j = 0; j < 8; j++) {
            float a = bias[j] + wk[0][j] * r0[j] + wk[1][j] * r1[j]
                    + wk[2][j] * r2[j] + wk[3][j] * cur[j];
            float sv = a / (1.f + __expf(-a));
            ov[j] = (short)f2b(sv);
        }
        *(short8*)(po + (size_t)i * DINNER) = ov;
        #pragma unroll
        for (int j = 0; j < 8; j++) { r0[j] = r1[j]; r1[j] = r2[j]; r2[j] = cur[j]; }
    }
}

// ---------------------------------------------------------------------------
// x_proj as MFMA GEMM: M=32768, N=32 (20 real + 12 zero), K=384.
// Writes fp32 xdb32 only (dt is computed inline in the scan kernels now).
// ---------------------------------------------------------------------------
__global__ __launch_bounds__(256) void k_xproj_mfma(const ushort* __restrict__ xa,
                                                    const ushort* __restrict__ xpwb,
                                                    float* __restrict__ xdb32) {
    __shared__ ushort As[128][40];
    __shared__ ushort Bs[32][40];
    int tid  = threadIdx.x;
    int lane = tid & 63;
    int wave = tid >> 6;
    int m0 = blockIdx.x * 128;
    float4v acc[2][2];
    #pragma unroll
    for (int i = 0; i < 2; i++)
        #pragma unroll
        for (int j = 0; j < 2; j++)
            acc[i][j] = (float4v){0.f, 0.f, 0.f, 0.f};
    for (int k0 = 0; k0 < 384; k0 += 32) {
        #pragma unroll
        for (int i = 0; i < 2; i++) {
            int idx = tid + i * 256;
            int r = idx >> 2, sg = idx & 3;
            *(short8*)&As[r][sg * 8] =
                *(const short8*)(xa + (size_t)(m0 + r) * 384 + k0 + sg * 8);
        }
        if (tid < 128) {
            int r = tid >> 2, sg = tid & 3;
            *(short8*)&Bs[r][sg * 8] =
                *(const short8*)(xpwb + (size_t)r * 384 + k0 + sg * 8);
        }
        __syncthreads();
        short8 av[2], bv[2];
        #pragma unroll
        for (int i = 0; i < 2; i++)
            av[i] = *(const short8*)&As[wave * 32 + i * 16 + (lane & 15)][(lane >> 4) * 8];
        #pragma unroll
        for (int j = 0; j < 2; j++)
            bv[j] = *(const short8*)&Bs[j * 16 + (lane & 15)][(lane >> 4) * 8];
        #pragma unroll
        for (int i = 0; i < 2; i++)
            #pragma unroll
            for (int j = 0; j < 2; j++)
                acc[i][j] = __builtin_amdgcn_mfma_f32_16x16x32_bf16(
                    av[i], bv[j], acc[i][j], 0, 0, 0);
        __syncthreads();
    }
    #pragma unroll
    for (int i = 0; i < 2; i++) {
        int rbase = m0 + wave * 32 + i * 16 + (lane >> 4) * 4;
        #pragma unroll
        for (int j = 0; j < 2; j++) {
            int col = j * 16 + (lane & 15);
            #pragma unroll
            for (int r = 0; r < 4; r++)
                xdb32[(size_t)(rbase + r) * 32 + col] = acc[i][j][r];
        }
    }
}

// ---------------------------------------------------------------------------
// Inline dt: softplus(sum_r row[r]*w[r] + bias). row[] is an LDS broadcast
// (same address across all lanes -> conflict-free); w[12]+bias in registers,
// loaded coalesced from dtwT[r][d]. ~20 VALU ops/elem vs 6 B/elem of dtv
// traffic (x3 uses) it replaces.
// ---------------------------------------------------------------------------
static __device__ __forceinline__ float dt_inline(const float* __restrict__ row,
                                                  const float* __restrict__ w,
                                                  float bias) {
    float s = bias;
    #pragma unroll
    for (int r = 0; r < DTRANK; r++) s += row[r] * w[r];
    return fmaxf(s, 0.f) + __logf(1.f + __expf(-fabsf(s)));
}

// ---------------------------------------------------------------------------
// Chunked scan pass 1: per-chunk local scan from h=0, dt computed inline.
// Carry layout chunk-major: carryH[(chunk*BB+b)*1536 + d*4+s] (float4 store),
// carryT = sum(dt) over chunk (A-prod recomputed as exp(As*T) in combine).
// ---------------------------------------------------------------------------
__global__ __launch_bounds__(384) void k_scan_local(const ushort* __restrict__ xa,
                                                    const float* __restrict__ xdb32,
                                                    const float* __restrict__ dtwT,
                                                    const float* __restrict__ dtb,
                                                    const float* __restrict__ A_log,
                                                    float* __restrict__ carryT,
                                                    float* __restrict__ carryH) {
    int d     = threadIdx.x;
    int chunk = blockIdx.x;
    int b     = blockIdx.y;
    __shared__ float rows[CLEN * 32];
    size_t rbase = ((size_t)b * LL + (size_t)chunk * CLEN) * 32;
    for (int i = d; i < CLEN * 32; i += 384) rows[i] = xdb32[rbase + i];
    float w[DTRANK];
    #pragma unroll
    for (int r = 0; r < DTRANK; r++) w[r] = dtwT[r * 384 + d];
    float bias = dtb[d];
    float As[DSTATE];
    #pragma unroll
    for (int s = 0; s < DSTATE; s++) As[s] = -__expf(A_log[d * DSTATE + s]);
    __syncthreads();
    float h[DSTATE] = {0.f, 0.f, 0.f, 0.f};
    float T = 0.f;
    size_t mbase = (size_t)b * LL + (size_t)chunk * CLEN;
    for (int l = 0; l < CLEN; l++) {
        size_t m = mbase + l;
        const float* row = &rows[l * 32];
        float dtvv = dt_inline(row, w, bias);
        float xav  = b2f(xa[m * DINNER + d]);
        float du   = dtvv * xav;
        T += dtvv;
        #pragma unroll
        for (int s = 0; s < DSTATE; s++) {
            float da = __expf(dtvv * As[s]);
            h[s] = da * h[s] + du * row[DTRANK + s];
        }
    }
    size_t cb = ((size_t)chunk * BB + b);
    carryT[cb * 384 + d] = T;
    float4v hv = {h[0], h[1], h[2], h[3]};
    *(float4v*)(carryH + cb * 1536 + d * 4) = hv;
}

// ---------------------------------------------------------------------------
// Pass 2: one thread per chain (b,d,s), serial over 128 chunks with
// coalesced per-step loads. A_k = exp(As * T_k). Writes incoming state
// (exclusive prefix) to carryI.
// ---------------------------------------------------------------------------
__global__ __launch_bounds__(256) void k_scan_combine(const float* __restrict__ carryT,
                                                      const float* __restrict__ carryH,
                                                      const float* __restrict__ A_log,
                                                      float* __restrict__ carryI) {
    int c   = blockIdx.x * 256 + threadIdx.x;   // 0..12287
    int b   = c / 1536;
    int rem = c - b * 1536;                     // d*4+s
    int d   = rem >> 2;
    float As = -__expf(A_log[rem]);
    float hrun = 0.f;
    for (int k = 0; k < NCHUNK; k++) {
        size_t o = (size_t)k * BB + b;
        float T  = carryT[o * 384 + d];
        float Hk = carryH[o * 1536 + rem];
        carryI[o * 1536 + rem] = hrun;
        hrun = __expf(As * T) * hrun + Hk;
    }
}

// ---------------------------------------------------------------------------
// Pass 3: seeded rerun (dt inline); y = h·C + xa*D, y *= silu(z); bf16 y.
// ---------------------------------------------------------------------------
__global__ __launch_bounds__(384) void k_scan_final(const ushort* __restrict__ xa,
                                                    const ushort* __restrict__ xz,
                                                    const float* __restrict__ xdb32,
                                                    const float* __restrict__ dtwT,
                                                    const float* __restrict__ dtb,
                                                    const float* __restrict__ A_log,
                                                    const float* __restrict__ Dp,
                                                    const float* __restrict__ carryI,
                                                    ushort* __restrict__ y) {
    int d     = threadIdx.x;
    int chunk = blockIdx.x;
    int b     = blockIdx.y;
    __shared__ float rows[CLEN * 32];
    size_t rbase = ((size_t)b * LL + (size_t)chunk * CLEN) * 32;
    for (int i = d; i < CLEN * 32; i += 384) rows[i] = xdb32[rbase + i];
    float w[DTRANK];
    #pragma unroll
    for (int r = 0; r < DTRANK; r++) w[r] = dtwT[r * 384 + d];
    float bias = dtb[d];
    float As[DSTATE];
    #pragma unroll
    for (int s = 0; s < DSTATE; s++) As[s] = -__expf(A_log[d * DSTATE + s]);
    float Dd = Dp[d];
    float4v hv = *(const float4v*)(carryI + ((size_t)chunk * BB + b) * 1536 + d * 4);
    float h[DSTATE];
    #pragma unroll
    for (int s = 0; s < DSTATE; s++) h[s] = hv[s];
    __syncthreads();
    size_t mbase = (size_t)b * LL + (size_t)chunk * CLEN;
    for (int l = 0; l < CLEN; l++) {
        size_t m = mbase + l;
        const float* row = &rows[l * 32];
        float dtvv = dt_inline(row, w, bias);
        float xav  = b2f(xa[m * DINNER + d]);
        float du   = dtvv * xav;
        float yv = 0.f;
        #pragma unroll
        for (int s = 0; s < DSTATE; s++) {
            float da = __expf(dtvv * As[s]);
            h[s] = da * h[s] + du * row[DTRANK + s];
            yv  += h[s] * row[DTRANK + DSTATE + s];
        }
        yv += xav * Dd;
        float zv = b2f(xz[m * 768 + DINNER + d]);
        yv *= zv / (1.f + __expf(-zv));
        y[m * DINNER + d] = f2b(yv);
    }
}

// ---------------------------------------------------------------------------
// Tail: low-rank (U,V) + residual(h0b, bf16) + LayerNorm; LDS-staged
// coalesced (B,C,L) writes.
// ---------------------------------------------------------------------------
__global__ __launch_bounds__(256) void k_tail(const ushort* __restrict__ h1b,
                                              const ushort* __restrict__ h0b,
                                              const float* __restrict__ U,
                                              const float* __restrict__ V,
                                              const float* __restrict__ g,
                                              const float* __restrict__ be,
                                              float* __restrict__ out) {
    __shared__ float tile[EMBED * 65];
    int tid  = threadIdx.x;
    int lane = tid & 63;
    int wave = tid >> 6;
    int b  = blockIdx.y;
    int l0 = blockIdx.x * 64;
    for (int t = 0; t < 16; t++) {
        int lloc = wave * 16 + t;
        size_t m = (size_t)b * LL + l0 + lloc;
        float hv[3];
        #pragma unroll
        for (int i = 0; i < 3; i++) hv[i] = b2f(h1b[m * EMBED + lane + 64 * i]);
        float r[RANK];
        #pragma unroll
        for (int j = 0; j < RANK; j++) {
            float p = 0.f;
            #pragma unroll
            for (int i = 0; i < 3; i++) p += hv[i] * U[j * EMBED + lane + 64 * i];
            #pragma unroll
            for (int off = 1; off < 64; off <<= 1) p += __shfl_xor(p, off);
            r[j] = p;
        }
        float u[3], s1 = 0.f, s2 = 0.f;
        #pragma unroll
        for (int i = 0; i < 3; i++) {
            int c = lane + 64 * i;
            float v = r[0] * V[c * 4 + 0] + r[1] * V[c * 4 + 1]
                    + r[2] * V[c * 4 + 2] + r[3] * V[c * 4 + 3];
            u[i] = v + b2f(h0b[m * EMBED + c]);
            s1 += u[i];
            s2 += u[i] * u[i];
        }
        #pragma unroll
        for (int off = 1; off < 64; off <<= 1) {
            s1 += __shfl_xor(s1, off);
            s2 += __shfl_xor(s2, off);
        }
        float mean = s1 * (1.f / EMBED);
        float var  = s2 * (1.f / EMBED) - mean * mean;
        float inv  = rsqrtf(var + 1e-5f);
        #pragma unroll
        for (int i = 0; i < 3; i++) {
            int c = lane + 64 * i;
            tile[c * 65 + lloc] = (u[i] - mean) * inv * g[c] + be[c];
        }
    }
    __syncthreads();
    for (int i = tid; i < EMBED * 64; i += 256) {
        int c = i >> 6, l = i & 63;
        out[((size_t)(b * EMBED + c)) * LL + l0 + l] = tile[c * 65 + l];
    }
}

// ---------------------------------------------------------------------------
extern "C" void kernel_launch(void* const* d_in, const int* in_sizes, int n_in,
                              void* d_out, int out_size, void* d_ws, size_t ws_size,
                              hipStream_t stream) {
    const float* x          = (const float*)d_in[0];
    const float* in_proj_w  = (const float*)d_in[1];
    const float* conv_w     = (const float*)d_in[2];
    const float* conv_b     = (const float*)d_in[3];
    const float* x_proj_w   = (const float*)d_in[4];
    const float* dt_proj_w  = (const float*)d_in[5];
    const float* dt_proj_b  = (const float*)d_in[6];
    const float* A_log      = (const float*)d_in[7];
    const float* Dp         = (const float*)d_in[8];
    const float* out_proj_w = (const float*)d_in[9];
    const float* U_w        = (const float*)d_in[10];
    const float* V_w        = (const float*)d_in[11];
    const float* ln_g       = (const float*)d_in[12];
    const float* ln_b       = (const float*)d_in[13];
    float* out = (float*)d_out;

    // Workspace layout.
    float* ws    = (float*)d_ws;
    float* xdb32 = ws;                                     // NBL*32 f32
    float* carryT = xdb32 + (size_t)NBL * 32;              // 128*8*384 f32
    float* carryH = carryT + (size_t)NCHUNK * BB * DINNER; // 128*8*1536 f32
    float* carryI = carryH + (size_t)NCHUNK * BB * DINNER * DSTATE;
    ushort* xz16   = (ushort*)(carryI + (size_t)NCHUNK * BB * DINNER * DSTATE);
    ushort* xa16   = xz16   + (size_t)NBL * 768;
    ushort* yb     = xa16   + (size_t)NBL * DINNER;
    ushort* h0b    = yb     + (size_t)NBL * DINNER;
    ushort* h1b    = h0b    + (size_t)NBL * EMBED;
    ushort* wi     = h1b    + (size_t)NBL * EMBED;         // 2*768*192
    ushort* wo     = wi     + (size_t)NMIX * 768 * EMBED;  // 2*192*384
    ushort* xpwb   = wo     + (size_t)NMIX * EMBED * DINNER; // 2*32*384
    float*  dtwT   = (float*)(xpwb + (size_t)NMIX * 32 * 384); // 2*12*384 f32
    float*  cwt    = dtwT + (size_t)NMIX * DTRANK * 384;       // 2*4*384 f32

    // fused weight prep (one launch)
    k_prep<<<(PREP_N0 + PREP_N1 + PREP_N2 + PREP_N3 + PREP_N4) / 256, 256, 0, stream>>>(
        in_proj_w, out_proj_w, x_proj_w, dt_proj_w, conv_w, wi, wo, xpwb, dtwT, cwt);

    k_transpose<<<dim3(LL / 32, EMBED / 32, BB), dim3(32, 8), 0, stream>>>(x, h0b);

    const ushort* hinb = h0b;
    for (int mix = 0; mix < NMIX; mix++) {
        const float* Alg  = A_log + (size_t)mix * DINNER * DSTATE;
        const float* dtwm = dtwT + (size_t)mix * DTRANK * 384;
        const float* dtbm = dt_proj_b + mix * DINNER;

        // in_proj -> xz bf16 (NBL,768)
        k_gemm_bf16<128, 2><<<dim3(768 / 128, NBL / 128), 256, 0, stream>>>(
            hinb, EMBED, wi + (size_t)mix * 768 * EMBED, EMBED,
            (float*)nullptr, 0, xz16, 768, EMBED);
        // conv + silu -> xa bf16 (sliding window, 8l x 8d per thread)
        k_conv_silu<<<(NBL / 8 * 48) / 256, 256, 0, stream>>>(
            xz16, cwt + (size_t)mix * DCONV * DINNER, conv_b + mix * DINNER, xa16);
        // x_proj MFMA -> xdb32 f32 only
        k_xproj_mfma<<<NBL / 128, 256, 0, stream>>>(
            xa16, xpwb + (size_t)mix * 32 * 384, xdb32);
        // chunked scan (dt inline, chunk-major carries)
        k_scan_local<<<dim3(NCHUNK, BB), 384, 0, stream>>>(
            xa16, xdb32, dtwm, dtbm, Alg, carryT, carryH);
        k_scan_combine<<<(BB * DINNER * DSTATE) / 256, 256, 0, stream>>>(
            carryT, carryH, Alg, carryI);
        k_scan_final<<<dim3(NCHUNK, BB), 384, 0, stream>>>(
            xa16, xz16, xdb32, dtwm, dtbm, Alg, Dp + mix * DINNER, carryI, yb);
        // out_proj -> h1b bf16 only
        k_gemm_bf16<64, 1><<<dim3(EMBED / 64, NBL / 128), 256, 0, stream>>>(
            yb, DINNER, wo + (size_t)mix * EMBED * DINNER, DINNER,
            (float*)nullptr, 0, h1b, EMBED, DINNER);
        hinb = h1b;
    }

    // tail: low-rank + residual(h0b) + LayerNorm -> out (B,C,H,W)
    k_tail<<<dim3(LL / 64, BB), 256, 0, stream>>>(h1b, h0b, U_w, V_w, ln_g, ln_b, out);
}

// Round 11
// 406.688 us; speedup vs baseline: 1.0756x; 1.0514x over previous
//
#include <hip/hip_runtime.h>
#include <hip/hip_bf16.h>
#include <cstdint>

// Problem constants
#define EMBED   192
#define DINNER  384
#define DSTATE  4
#define DCONV   4
#define DTRANK  12
#define NMIX    2
#define RANK    4
#define BB      8
#define LL      4096            // H*W = 64*64
#define NBL     (BB*LL)         // 32768 rows
#define NCHUNK  128
#define CLEN    32              // LL / NCHUNK
#define RSTR    36              // rows LDS stride (pad: b128-aligned, <=2-way banks)

typedef __attribute__((ext_vector_type(8))) short short8;
typedef __attribute__((ext_vector_type(4))) float float4v;

static __device__ __forceinline__ ushort f2b(float f) {
    __hip_bfloat16 h = __float2bfloat16(f);
    return *(ushort*)&h;
}
static __device__ __forceinline__ float b2f(ushort u) {
    __hip_bfloat16 h;
    *(ushort*)&h = u;
    return __bfloat162float(h);
}
static __device__ __forceinline__ float bs2f(short s) {
    ushort u = (ushort)s;
    return b2f(u);
}

// ---------------------------------------------------------------------------
// Fused weight prep (one launch): wi cast | wo cast | xpw pad | dtw pad | cwT
// Region sizes: 294912 | 147456 | 24576 | 24576 | 3072
// ---------------------------------------------------------------------------
#define PREP_N0 294912
#define PREP_N1 147456
#define PREP_N2 24576
#define PREP_N3 24576
#define PREP_N4 3072
__global__ __launch_bounds__(256) void k_prep(const float* __restrict__ in_proj_w,
                                              const float* __restrict__ out_proj_w,
                                              const float* __restrict__ x_proj_w,
                                              const float* __restrict__ dt_proj_w,
                                              const float* __restrict__ conv_w,
                                              ushort* __restrict__ wi,
                                              ushort* __restrict__ wo,
                                              ushort* __restrict__ xpwb,
                                              ushort* __restrict__ dtwpad,
                                              float* __restrict__ cwt) {
    int i = blockIdx.x * 256 + threadIdx.x;
    if (i < PREP_N0) {
        wi[i] = f2b(in_proj_w[i]);
        return;
    }
    i -= PREP_N0;
    if (i < PREP_N1) {
        wo[i] = f2b(out_proj_w[i]);
        return;
    }
    i -= PREP_N1;
    if (i < PREP_N2) {
        int mix = i / (32 * 384);
        int rem = i % (32 * 384);
        int e = rem / 384, k = rem % 384;
        xpwb[i] = (e < 20) ? f2b(x_proj_w[(size_t)mix * 20 * 384 + e * 384 + k]) : (ushort)0;
        return;
    }
    i -= PREP_N2;
    if (i < PREP_N3) {
        // dtwpad[mix][d][r], r zero-padded 12..31 (B-side zeros => K=32 exact)
        int mix = i / (384 * 32);
        int rem = i % (384 * 32);
        int n = rem / 32, r = rem % 32;
        dtwpad[i] = (r < DTRANK) ? f2b(dt_proj_w[(size_t)mix * 384 * DTRANK + n * DTRANK + r])
                                 : (ushort)0;
        return;
    }
    i -= PREP_N3;
    if (i < PREP_N4) {
        int mix = i / (DCONV * DINNER);
        int rem = i % (DCONV * DINNER);
        int k = rem / DINNER, d = rem % DINNER;
        cwt[i] = conv_w[(size_t)mix * DINNER * DCONV + d * DCONV + k];
    }
}

// ---------------------------------------------------------------------------
// Transpose (B, C, L) -> (B, L, C) bf16 (GEMM A operand + tail residual)
// ---------------------------------------------------------------------------
__global__ __launch_bounds__(256) void k_transpose(const float* __restrict__ x,
                                                   ushort* __restrict__ h0b) {
    __shared__ float tile[32][33];
    int b  = blockIdx.z;
    int c0 = blockIdx.y * 32;
    int l0 = blockIdx.x * 32;
    int tx = threadIdx.x;       // 0..31
    int ty = threadIdx.y;       // 0..7
    #pragma unroll
    for (int i = 0; i < 4; i++) {
        int c = c0 + ty + i * 8;
        tile[ty + i * 8][tx] = x[((size_t)b * EMBED + c) * LL + l0 + tx];
    }
    __syncthreads();
    #pragma unroll
    for (int i = 0; i < 4; i++) {
        int l = l0 + ty + i * 8;
        h0b[((size_t)b * LL + l) * EMBED + c0 + tx] = f2b(tile[tx][ty + i * 8]);
    }
}

// ---------------------------------------------------------------------------
// bf16 MFMA GEMM, NT: C[m,n] = sum_k A[m,k]*B[n,k]. M=32768 (grid.y*128).
// TN in {128 (WRN=2), 64 (WRN=1)}. BK=32. Writes fp32 C and/or bf16 Cb.
// ---------------------------------------------------------------------------
template<int TN, int WRN>
__global__ __launch_bounds__(256) void k_gemm_bf16(const ushort* __restrict__ A, int lda,
                                                   const ushort* __restrict__ Bw, int ldb,
                                                   float* __restrict__ C, int ldc,
                                                   ushort* __restrict__ Cb, int ldcb,
                                                   int K) {
    constexpr int WRM = 4 / WRN;
    constexpr int WM  = 128 / WRM;
    constexpr int MT  = WM / 16;
    __shared__ ushort As[128][40];
    __shared__ ushort Bs[TN][40];
    int tid  = threadIdx.x;
    int lane = tid & 63;
    int wave = tid >> 6;
    int wmo = (wave / WRN) * WM;
    int wno = (wave % WRN) * 64;
    int m0 = blockIdx.y * 128;
    int n0 = blockIdx.x * TN;

    float4v acc[MT][4];
    #pragma unroll
    for (int i = 0; i < MT; i++)
        #pragma unroll
        for (int j = 0; j < 4; j++)
            acc[i][j] = (float4v){0.f, 0.f, 0.f, 0.f};

    for (int k0 = 0; k0 < K; k0 += 32) {
        #pragma unroll
        for (int i = 0; i < 2; i++) {
            int idx = tid + i * 256;
            int r = idx >> 2, sg = idx & 3;
            *(short8*)&As[r][sg * 8] =
                *(const short8*)(A + (size_t)(m0 + r) * lda + k0 + sg * 8);
        }
        #pragma unroll
        for (int i = 0; i < TN / 64; i++) {
            int idx = tid + i * 256;
            int r = idx >> 2, sg = idx & 3;
            *(short8*)&Bs[r][sg * 8] =
                *(const short8*)(Bw + (size_t)(n0 + r) * ldb + k0 + sg * 8);
        }
        __syncthreads();
        short8 av[MT], bv[4];
        #pragma unroll
        for (int i = 0; i < MT; i++)
            av[i] = *(const short8*)&As[wmo + i * 16 + (lane & 15)][(lane >> 4) * 8];
        #pragma unroll
        for (int j = 0; j < 4; j++)
            bv[j] = *(const short8*)&Bs[wno + j * 16 + (lane & 15)][(lane >> 4) * 8];
        #pragma unroll
        for (int i = 0; i < MT; i++)
            #pragma unroll
            for (int j = 0; j < 4; j++)
                acc[i][j] = __builtin_amdgcn_mfma_f32_16x16x32_bf16(
                    av[i], bv[j], acc[i][j], 0, 0, 0);
        __syncthreads();
    }

    #pragma unroll
    for (int i = 0; i < MT; i++) {
        int rbase = m0 + wmo + i * 16 + (lane >> 4) * 4;
        #pragma unroll
        for (int j = 0; j < 4; j++) {
            int col = n0 + wno + j * 16 + (lane & 15);
            #pragma unroll
            for (int r = 0; r < 4; r++) {
                float v = acc[i][j][r];
                if (C)  C[(size_t)(rbase + r) * ldc + col] = v;
                if (Cb) Cb[(size_t)(rbase + r) * ldcb + col] = f2b(v);
            }
        }
    }
}

// ---------------------------------------------------------------------------
// Depthwise causal conv (width 4) + bias + SiLU.
// Thread owns 8 consecutive d x 8 consecutive l; sliding 4-row window in
// registers. Weights via transposed cwT (coalesced), paid once per 64 outputs.
// ---------------------------------------------------------------------------
__global__ __launch_bounds__(256) void k_conv_silu(const ushort* __restrict__ xz,
                                                   const float* __restrict__ cwt,
                                                   const float* __restrict__ cb,
                                                   ushort* __restrict__ xa) {
    int t   = blockIdx.x * 256 + threadIdx.x;   // over (NBL/8)*48
    int g   = t % 48;
    int blc = t / 48;
    int d0  = g * 8;
    int lc  = blc % (LL / 8);
    int b   = blc / (LL / 8);
    int l0  = lc * 8;

    float wk[4][8], bias[8];
    #pragma unroll
    for (int k = 0; k < 4; k++) {
        float4v wa = *(const float4v*)(cwt + k * DINNER + d0);
        float4v wb = *(const float4v*)(cwt + k * DINNER + d0 + 4);
        #pragma unroll
        for (int j = 0; j < 4; j++) { wk[k][j] = wa[j]; wk[k][j + 4] = wb[j]; }
    }
    {
        float4v ba = *(const float4v*)(cb + d0);
        float4v bb = *(const float4v*)(cb + d0 + 4);
        #pragma unroll
        for (int j = 0; j < 4; j++) { bias[j] = ba[j]; bias[j + 4] = bb[j]; }
    }

    float r0[8] = {}, r1[8] = {}, r2[8] = {};
    const ushort* px = xz + ((size_t)(b * LL + l0)) * 768 + d0;
    if (l0 > 0) {
        short8 v;
        v = *(const short8*)(px - 3 * 768);
        #pragma unroll
        for (int j = 0; j < 8; j++) r0[j] = bs2f(v[j]);
        v = *(const short8*)(px - 2 * 768);
        #pragma unroll
        for (int j = 0; j < 8; j++) r1[j] = bs2f(v[j]);
        v = *(const short8*)(px - 1 * 768);
        #pragma unroll
        for (int j = 0; j < 8; j++) r2[j] = bs2f(v[j]);
    }
    ushort* po = xa + ((size_t)(b * LL + l0)) * DINNER + d0;
    #pragma unroll
    for (int i = 0; i < 8; i++) {
        short8 v = *(const short8*)(px + (size_t)i * 768);
        float cur[8];
        #pragma unroll
        for (int j = 0; j < 8; j++) cur[j] = bs2f(v[j]);
        short8 ov;
        #pragma unroll
        for (int j = 0; j < 8; j++) {
            float a = bias[j] + wk[0][j] * r0[j] + wk[1][j] * r1[j]
                    + wk[2][j] * r2[j] + wk[3][j] * cur[j];
            float sv = a / (1.f + __expf(-a));
            ov[j] = (short)f2b(sv);
        }
        *(short8*)(po + (size_t)i * DINNER) = ov;
        #pragma unroll
        for (int j = 0; j < 8; j++) { r0[j] = r1[j]; r1[j] = r2[j]; r2[j] = cur[j]; }
    }
}

// ---------------------------------------------------------------------------
// x_proj as MFMA GEMM: M=32768, N=32 (20 real + 12 zero), K=384.
// Writes fp32 xdb32 only (cols 20..31 are exact zeros — used as dt K-pad).
// ---------------------------------------------------------------------------
__global__ __launch_bounds__(256) void k_xproj_mfma(const ushort* __restrict__ xa,
                                                    const ushort* __restrict__ xpwb,
                                                    float* __restrict__ xdb32) {
    __shared__ ushort As[128][40];
    __shared__ ushort Bs[32][40];
    int tid  = threadIdx.x;
    int lane = tid & 63;
    int wave = tid >> 6;
    int m0 = blockIdx.x * 128;
    float4v acc[2][2];
    #pragma unroll
    for (int i = 0; i < 2; i++)
        #pragma unroll
        for (int j = 0; j < 2; j++)
            acc[i][j] = (float4v){0.f, 0.f, 0.f, 0.f};
    for (int k0 = 0; k0 < 384; k0 += 32) {
        #pragma unroll
        for (int i = 0; i < 2; i++) {
            int idx = tid + i * 256;
            int r = idx >> 2, sg = idx & 3;
            *(short8*)&As[r][sg * 8] =
                *(const short8*)(xa + (size_t)(m0 + r) * 384 + k0 + sg * 8);
        }
        if (tid < 128) {
            int r = tid >> 2, sg = tid & 3;
            *(short8*)&Bs[r][sg * 8] =
                *(const short8*)(xpwb + (size_t)r * 384 + k0 + sg * 8);
        }
        __syncthreads();
        short8 av[2], bv[2];
        #pragma unroll
        for (int i = 0; i < 2; i++)
            av[i] = *(const short8*)&As[wave * 32 + i * 16 + (lane & 15)][(lane >> 4) * 8];
        #pragma unroll
        for (int j = 0; j < 2; j++)
            bv[j] = *(const short8*)&Bs[j * 16 + (lane & 15)][(lane >> 4) * 8];
        #pragma unroll
        for (int i = 0; i < 2; i++)
            #pragma unroll
            for (int j = 0; j < 2; j++)
                acc[i][j] = __builtin_amdgcn_mfma_f32_16x16x32_bf16(
                    av[i], bv[j], acc[i][j], 0, 0, 0);
        __syncthreads();
    }
    #pragma unroll
    for (int i = 0; i < 2; i++) {
        int rbase = m0 + wave * 32 + i * 16 + (lane >> 4) * 4;
        #pragma unroll
        for (int j = 0; j < 2; j++) {
            int col = j * 16 + (lane & 15);
            #pragma unroll
            for (int r = 0; r < 4; r++)
                xdb32[(size_t)(rbase + r) * 32 + col] = acc[i][j][r];
        }
    }
}

// ---------------------------------------------------------------------------
// In-block dt tile via MFMA: dt[l][d] = softplus(rows[l][0:12] . dtw[d][0:12]
// + bias[d]), K padded to 32 (rows cols 20..31 are zeros * dtw pad zeros).
// 48 MFMAs/block (8/wave) replace ~12 VALU FMA per (l,d). Result -> LDS bf16.
// Caller must __syncthreads() after (and have rows staged+synced before).
// ---------------------------------------------------------------------------
static __device__ __forceinline__ void dt_mfma_tile(const float* __restrict__ rows,
                                                    const ushort* __restrict__ dtwpad,
                                                    const float* __restrict__ dtb,
                                                    ushort* __restrict__ dtS,
                                                    int wave, int lane) {
    int mcol = lane & 15;
    int quad = lane >> 4;
    #pragma unroll
    for (int nt = 0; nt < 4; nt++) {
        int n = wave * 64 + nt * 16 + mcol;
        short8 bv = *(const short8*)(dtwpad + (size_t)n * 32 + quad * 8);
        float bias = dtb[n];
        #pragma unroll
        for (int mt = 0; mt < 2; mt++) {
            float4v a0 = *(const float4v*)&rows[(mt * 16 + mcol) * RSTR + quad * 8];
            float4v a1 = *(const float4v*)&rows[(mt * 16 + mcol) * RSTR + quad * 8 + 4];
            short8 av;
            #pragma unroll
            for (int j = 0; j < 4; j++) {
                av[j]     = (short)f2b(a0[j]);
                av[j + 4] = (short)f2b(a1[j]);
            }
            float4v acc = (float4v){0.f, 0.f, 0.f, 0.f};
            acc = __builtin_amdgcn_mfma_f32_16x16x32_bf16(av, bv, acc, 0, 0, 0);
            #pragma unroll
            for (int r = 0; r < 4; r++) {
                float s = acc[r] + bias;
                float sp = fmaxf(s, 0.f) + __logf(1.f + __expf(-fabsf(s)));
                dtS[(mt * 16 + quad * 4 + r) * DINNER + n] = f2b(sp);
            }
        }
    }
}

// Adaptive state-decay: if As = (1,2,3,4)*As0 (true for this model's A_log),
// 4 exps collapse to 1 exp + 3 muls. Generic fallback otherwise.
static __device__ __forceinline__ bool as_is_harmonic(const float* As) {
    return fabsf(As[1] - 2.f * As[0]) <= 1e-5f * fabsf(As[1]) + 1e-12f
        && fabsf(As[2] - 3.f * As[0]) <= 1e-5f * fabsf(As[2]) + 1e-12f
        && fabsf(As[3] - 4.f * As[0]) <= 1e-5f * fabsf(As[3]) + 1e-12f;
}

// ---------------------------------------------------------------------------
// Chunked scan pass 1: per-chunk local scan from h=0; dt tile via MFMA.
// Carries chunk-major: carryH[(chunk*BB+b)*1536 + d*4+s], carryT = sum(dt).
// ---------------------------------------------------------------------------
__global__ __launch_bounds__(384) void k_scan_local(const ushort* __restrict__ xa,
                                                    const float* __restrict__ xdb32,
                                                    const ushort* __restrict__ dtwpad,
                                                    const float* __restrict__ dtb,
                                                    const float* __restrict__ A_log,
                                                    float* __restrict__ carryT,
                                                    float* __restrict__ carryH) {
    int d     = threadIdx.x;
    int lane  = d & 63;
    int wave  = d >> 6;
    int chunk = blockIdx.x;
    int b     = blockIdx.y;
    __shared__ float rows[CLEN * RSTR];
    __shared__ ushort dtS[CLEN * DINNER];
    size_t rbase = ((size_t)b * LL + (size_t)chunk * CLEN) * 32;
    for (int i = d; i < CLEN * 32; i += 384) {
        int l = i >> 5, e = i & 31;
        rows[l * RSTR + e] = xdb32[rbase + i];
    }
    float As[DSTATE];
    #pragma unroll
    for (int s = 0; s < DSTATE; s++) As[s] = -__expf(A_log[d * DSTATE + s]);
    bool fastA = as_is_harmonic(As);
    __syncthreads();
    dt_mfma_tile(rows, dtwpad, dtb, dtS, wave, lane);
    __syncthreads();
    float h[DSTATE] = {0.f, 0.f, 0.f, 0.f};
    float T = 0.f;
    size_t mbase = (size_t)b * LL + (size_t)chunk * CLEN;
    for (int l = 0; l < CLEN; l++) {
        float dtvv = b2f(dtS[l * DINNER + d]);
        float xav  = b2f(xa[(mbase + l) * DINNER + d]);
        float du   = dtvv * xav;
        T += dtvv;
        const float* row = &rows[l * RSTR];
        float da[DSTATE];
        if (fastA) {
            float p = __expf(dtvv * As[0]);
            da[0] = p; da[1] = p * p; da[2] = da[1] * p; da[3] = da[2] * p;
        } else {
            #pragma unroll
            for (int s = 0; s < DSTATE; s++) da[s] = __expf(dtvv * As[s]);
        }
        #pragma unroll
        for (int s = 0; s < DSTATE; s++)
            h[s] = da[s] * h[s] + du * row[DTRANK + s];
    }
    size_t cb = ((size_t)chunk * BB + b);
    carryT[cb * 384 + d] = T;
    float4v hv = {h[0], h[1], h[2], h[3]};
    *(float4v*)(carryH + cb * 1536 + d * 4) = hv;
}

// ---------------------------------------------------------------------------
// Pass 2: one thread per chain (b,d,s), serial over 128 chunks, coalesced
// per-step loads. A_k = exp(As*T_k). Writes incoming state to carryI.
// ---------------------------------------------------------------------------
__global__ __launch_bounds__(256) void k_scan_combine(const float* __restrict__ carryT,
                                                      const float* __restrict__ carryH,
                                                      const float* __restrict__ A_log,
                                                      float* __restrict__ carryI) {
    int c   = blockIdx.x * 256 + threadIdx.x;   // 0..12287
    int b   = c / 1536;
    int rem = c - b * 1536;                     // d*4+s
    int d   = rem >> 2;
    float As = -__expf(A_log[rem]);
    float hrun = 0.f;
    for (int k = 0; k < NCHUNK; k++) {
        size_t o = (size_t)k * BB + b;
        float T  = carryT[o * 384 + d];
        float Hk = carryH[o * 1536 + rem];
        carryI[o * 1536 + rem] = hrun;
        hrun = __expf(As * T) * hrun + Hk;
    }
}

// ---------------------------------------------------------------------------
// Pass 3: seeded rerun (dt via MFMA tile); y = h·C + xa*D, y *= silu(z).
// ---------------------------------------------------------------------------
__global__ __launch_bounds__(384) void k_scan_final(const ushort* __restrict__ xa,
                                                    const ushort* __restrict__ xz,
                                                    const float* __restrict__ xdb32,
                                                    const ushort* __restrict__ dtwpad,
                                                    const float* __restrict__ dtb,
                                                    const float* __restrict__ A_log,
                                                    const float* __restrict__ Dp,
                                                    const float* __restrict__ carryI,
                                                    ushort* __restrict__ y) {
    int d     = threadIdx.x;
    int lane  = d & 63;
    int wave  = d >> 6;
    int chunk = blockIdx.x;
    int b     = blockIdx.y;
    __shared__ float rows[CLEN * RSTR];
    __shared__ ushort dtS[CLEN * DINNER];
    size_t rbase = ((size_t)b * LL + (size_t)chunk * CLEN) * 32;
    for (int i = d; i < CLEN * 32; i += 384) {
        int l = i >> 5, e = i & 31;
        rows[l * RSTR + e] = xdb32[rbase + i];
    }
    float As[DSTATE];
    #pragma unroll
    for (int s = 0; s < DSTATE; s++) As[s] = -__expf(A_log[d * DSTATE + s]);
    bool fastA = as_is_harmonic(As);
    float Dd = Dp[d];
    float4v hv = *(const float4v*)(carryI + ((size_t)chunk * BB + b) * 1536 + d * 4);
    float h[DSTATE];
    #pragma unroll
    for (int s = 0; s < DSTATE; s++) h[s] = hv[s];
    __syncthreads();
    dt_mfma_tile(rows, dtwpad, dtb, dtS, wave, lane);
    __syncthreads();
    size_t mbase = (size_t)b * LL + (size_t)chunk * CLEN;
    for (int l = 0; l < CLEN; l++) {
        size_t m = mbase + l;
        float dtvv = b2f(dtS[l * DINNER + d]);
        float xav  = b2f(xa[m * DINNER + d]);
        float du   = dtvv * xav;
        const float* row = &rows[l * RSTR];
        float da[DSTATE];
        if (fastA) {
            float p = __expf(dtvv * As[0]);
            da[0] = p; da[1] = p * p; da[2] = da[1] * p; da[3] = da[2] * p;
        } else {
            #pragma unroll
            for (int s = 0; s < DSTATE; s++) da[s] = __expf(dtvv * As[s]);
        }
        float yv = 0.f;
        #pragma unroll
        for (int s = 0; s < DSTATE; s++) {
            h[s] = da[s] * h[s] + du * row[DTRANK + s];
            yv  += h[s] * row[DTRANK + DSTATE + s];
        }
        yv += xav * Dd;
        float zv = b2f(xz[m * 768 + DINNER + d]);
        yv *= zv / (1.f + __expf(-zv));
        y[m * DINNER + d] = f2b(yv);
    }
}

// ---------------------------------------------------------------------------
// Tail: low-rank (U,V) + residual(h0b, bf16) + LayerNorm; LDS-staged
// coalesced (B,C,L) writes.
// ---------------------------------------------------------------------------
__global__ __launch_bounds__(256) void k_tail(const ushort* __restrict__ h1b,
                                              const ushort* __restrict__ h0b,
                                              const float* __restrict__ U,
                                              const float* __restrict__ V,
                                              const float* __restrict__ g,
                                              const float* __restrict__ be,
                                              float* __restrict__ out) {
    __shared__ float tile[EMBED * 65];
    int tid  = threadIdx.x;
    int lane = tid & 63;
    int wave = tid >> 6;
    int b  = blockIdx.y;
    int l0 = blockIdx.x * 64;
    for (int t = 0; t < 16; t++) {
        int lloc = wave * 16 + t;
        size_t m = (size_t)b * LL + l0 + lloc;
        float hv[3];
        #pragma unroll
        for (int i = 0; i < 3; i++) hv[i] = b2f(h1b[m * EMBED + lane + 64 * i]);
        float r[RANK];
        #pragma unroll
        for (int j = 0; j < RANK; j++) {
            float p = 0.f;
            #pragma unroll
            for (int i = 0; i < 3; i++) p += hv[i] * U[j * EMBED + lane + 64 * i];
            #pragma unroll
            for (int off = 1; off < 64; off <<= 1) p += __shfl_xor(p, off);
            r[j] = p;
        }
        float u[3], s1 = 0.f, s2 = 0.f;
        #pragma unroll
        for (int i = 0; i < 3; i++) {
            int c = lane + 64 * i;
            float v = r[0] * V[c * 4 + 0] + r[1] * V[c * 4 + 1]
                    + r[2] * V[c * 4 + 2] + r[3] * V[c * 4 + 3];
            u[i] = v + b2f(h0b[m * EMBED + c]);
            s1 += u[i];
            s2 += u[i] * u[i];
        }
        #pragma unroll
        for (int off = 1; off < 64; off <<= 1) {
            s1 += __shfl_xor(s1, off);
            s2 += __shfl_xor(s2, off);
        }
        float mean = s1 * (1.f / EMBED);
        float var  = s2 * (1.f / EMBED) - mean * mean;
        float inv  = rsqrtf(var + 1e-5f);
        #pragma unroll
        for (int i = 0; i < 3; i++) {
            int c = lane + 64 * i;
            tile[c * 65 + lloc] = (u[i] - mean) * inv * g[c] + be[c];
        }
    }
    __syncthreads();
    for (int i = tid; i < EMBED * 64; i += 256) {
        int c = i >> 6, l = i & 63;
        out[((size_t)(b * EMBED + c)) * LL + l0 + l] = tile[c * 65 + l];
    }
}

// ---------------------------------------------------------------------------
extern "C" void kernel_launch(void* const* d_in, const int* in_sizes, int n_in,
                              void* d_out, int out_size, void* d_ws, size_t ws_size,
                              hipStream_t stream) {
    const float* x          = (const float*)d_in[0];
    const float* in_proj_w  = (const float*)d_in[1];
    const float* conv_w     = (const float*)d_in[2];
    const float* conv_b     = (const float*)d_in[3];
    const float* x_proj_w   = (const float*)d_in[4];
    const float* dt_proj_w  = (const float*)d_in[5];
    const float* dt_proj_b  = (const float*)d_in[6];
    const float* A_log      = (const float*)d_in[7];
    const float* Dp         = (const float*)d_in[8];
    const float* out_proj_w = (const float*)d_in[9];
    const float* U_w        = (const float*)d_in[10];
    const float* V_w        = (const float*)d_in[11];
    const float* ln_g       = (const float*)d_in[12];
    const float* ln_b       = (const float*)d_in[13];
    float* out = (float*)d_out;

    // Workspace layout.
    float* ws    = (float*)d_ws;
    float* xdb32 = ws;                                     // NBL*32 f32
    float* carryT = xdb32 + (size_t)NBL * 32;              // 128*8*384 f32
    float* carryH = carryT + (size_t)NCHUNK * BB * DINNER; // 128*8*1536 f32
    float* carryI = carryH + (size_t)NCHUNK * BB * DINNER * DSTATE;
    ushort* xz16   = (ushort*)(carryI + (size_t)NCHUNK * BB * DINNER * DSTATE);
    ushort* xa16   = xz16   + (size_t)NBL * 768;
    ushort* yb     = xa16   + (size_t)NBL * DINNER;
    ushort* h0b    = yb     + (size_t)NBL * DINNER;
    ushort* h1b    = h0b    + (size_t)NBL * EMBED;
    ushort* wi     = h1b    + (size_t)NBL * EMBED;         // 2*768*192
    ushort* wo     = wi     + (size_t)NMIX * 768 * EMBED;  // 2*192*384
    ushort* xpwb   = wo     + (size_t)NMIX * EMBED * DINNER; // 2*32*384
    ushort* dtwpad = xpwb   + (size_t)NMIX * 32 * 384;       // 2*384*32
    float*  cwt    = (float*)(dtwpad + (size_t)NMIX * 384 * 32); // 2*4*384 f32

    // fused weight prep (one launch)
    k_prep<<<(PREP_N0 + PREP_N1 + PREP_N2 + PREP_N3 + PREP_N4) / 256, 256, 0, stream>>>(
        in_proj_w, out_proj_w, x_proj_w, dt_proj_w, conv_w, wi, wo, xpwb, dtwpad, cwt);

    k_transpose<<<dim3(LL / 32, EMBED / 32, BB), dim3(32, 8), 0, stream>>>(x, h0b);

    const ushort* hinb = h0b;
    for (int mix = 0; mix < NMIX; mix++) {
        const float* Alg  = A_log + (size_t)mix * DINNER * DSTATE;
        const ushort* dtwm = dtwpad + (size_t)mix * 384 * 32;
        const float* dtbm = dt_proj_b + mix * DINNER;

        // in_proj -> xz bf16 (NBL,768)
        k_gemm_bf16<128, 2><<<dim3(768 / 128, NBL / 128), 256, 0, stream>>>(
            hinb, EMBED, wi + (size_t)mix * 768 * EMBED, EMBED,
            (float*)nullptr, 0, xz16, 768, EMBED);
        // conv + silu -> xa bf16 (sliding window, 8l x 8d per thread)
        k_conv_silu<<<(NBL / 8 * 48) / 256, 256, 0, stream>>>(
            xz16, cwt + (size_t)mix * DCONV * DINNER, conv_b + mix * DINNER, xa16);
        // x_proj MFMA -> xdb32 f32 only
        k_xproj_mfma<<<NBL / 128, 256, 0, stream>>>(
            xa16, xpwb + (size_t)mix * 32 * 384, xdb32);
        // chunked scan (dt via in-block MFMA, chunk-major carries)
        k_scan_local<<<dim3(NCHUNK, BB), 384, 0, stream>>>(
            xa16, xdb32, dtwm, dtbm, Alg, carryT, carryH);
        k_scan_combine<<<(BB * DINNER * DSTATE) / 256, 256, 0, stream>>>(
            carryT, carryH, Alg, carryI);
        k_scan_final<<<dim3(NCHUNK, BB), 384, 0, stream>>>(
            xa16, xz16, xdb32, dtwm, dtbm, Alg, Dp + mix * DINNER, carryI, yb);
        // out_proj -> h1b bf16 only
        k_gemm_bf16<64, 1><<<dim3(EMBED / 64, NBL / 128), 256, 0, stream>>>(
            yb, DINNER, wo + (size_t)mix * EMBED * DINNER, DINNER,
            (float*)nullptr, 0, h1b, EMBED, DINNER);
        hinb = h1b;
    }

    // tail: low-rank + residual(h0b) + LayerNorm -> out (B,C,H,W)
    k_tail<<<dim3(LL / 64, BB), 256, 0, stream>>>(h1b, h0b, U_w, V_w, ln_g, ln_b, out);
}